// Round 10
// baseline (533.348 us; speedup 1.0000x reference)
//
#include <hip/hip_runtime.h>
#include <math.h>

// ---------------------------------------------------------------------------
// GraphNewPolicyNetwork: 2x GCNConv(improved=True) + MLP head + sigmoid +
// gumbel-softmax(hard) straight-through indicator.
// N=100000 nodes, E=1600000 edges, D=H1=H2=64, M1=128, M2=64.
// Outputs: d_out[0:N] = prob (f32), d_out[N:2N] = ind (f32, 0/1).
//
// Round 10: fusion. K2 = agg1 -> LDS -> gemm2 (h1 never hits HBM);
// K3 = agg2 -> LDS (head Xs upper half, pre-swizzled) -> head (h2 never hits
// HBM). Head za/zb x-reads upgraded to b128 quad-k (LDS was the bound at 54%
// VALUBusy; -24% LDS cycles), same ascending-k FMA order -> bitwise-stable.
// ---------------------------------------------------------------------------

// ----------------------------- threefry2x32 --------------------------------
__device__ __forceinline__ unsigned rotl32(unsigned x, int r) {
  return (x << r) | (x >> (32 - r));
}

// JAX threefry2x32 (20 rounds), matches jax/_src/prng.py
__device__ __forceinline__ void threefry2x32(unsigned k0, unsigned k1,
                                             unsigned x0, unsigned x1,
                                             unsigned& o0, unsigned& o1) {
  unsigned ks2 = k0 ^ k1 ^ 0x1BD11BDAu;
#define TF_RND(r) { x0 += x1; x1 = rotl32(x1, (r)); x1 ^= x0; }
  x0 += k0; x1 += k1;
  TF_RND(13) TF_RND(15) TF_RND(26) TF_RND(6)
  x0 += k1; x1 += ks2 + 1u;
  TF_RND(17) TF_RND(29) TF_RND(16) TF_RND(24)
  x0 += ks2; x1 += k0 + 2u;
  TF_RND(13) TF_RND(15) TF_RND(26) TF_RND(6)
  x0 += k0; x1 += k1 + 3u;
  TF_RND(17) TF_RND(29) TF_RND(16) TF_RND(24)
  x0 += k1; x1 += ks2 + 4u;
  TF_RND(13) TF_RND(15) TF_RND(26) TF_RND(6)
  x0 += ks2; x1 += k0 + 5u;
#undef TF_RND
  o0 = x0; o1 = x1;
}

// Partitionable threefry bits: element flat index j -> counter (0, j),
// 32-bit output = out0 ^ out1.
__device__ __forceinline__ unsigned jax_random_bits_u32(unsigned k0, unsigned k1,
                                                        unsigned flat_idx) {
  unsigned a, b;
  threefry2x32(k0, k1, 0u, flat_idx, a, b);
  return a ^ b;
}

// --------------------------- bucketed CSR build ----------------------------
// bucket(d) = d >> 8  (256 nodes per bucket, NBUCK = ceil(N/256) <= 512).
// Packed edge: (dlocal << 20) | src   (requires src < 2^20, dlocal < 2^12).
#define BSHIFT 8
#define BMASK 255

// Per-block LDS histogram of buckets, merged into global coarse[].
__global__ __launch_bounds__(256) void coarse_hist_kernel(
    const int* __restrict__ dst, int* __restrict__ coarse, int E) {
  __shared__ int h[512];
  for (int i = threadIdx.x; i < 512; i += 256) h[i] = 0;
  __syncthreads();
  for (int e = blockIdx.x * blockDim.x + threadIdx.x; e < E;
       e += gridDim.x * blockDim.x)
    atomicAdd(&h[dst[e] >> BSHIFT], 1);
  __syncthreads();
  for (int i = threadIdx.x; i < 512; i += 256)
    if (h[i]) atomicAdd(&coarse[i], h[i]);
}

// Single block: exclusive scan of coarse -> bbase (bucket ranges) and cbase
// (scatter cursors).
__global__ __launch_bounds__(512) void coarse_scan_kernel(
    const int* __restrict__ coarse, int* __restrict__ bbase,
    int* __restrict__ cbase, int NBUCK) {
  __shared__ int sh[512];
  int t = threadIdx.x;
  int v = (t < NBUCK) ? coarse[t] : 0;
  sh[t] = v;
  __syncthreads();
  for (int o = 1; o < 512; o <<= 1) {
    int a = (t >= o) ? sh[t - o] : 0;
    __syncthreads();
    sh[t] += a;
    __syncthreads();
  }
  if (t < NBUCK) {
    int ex = sh[t] - v;
    bbase[t] = ex;
    cbase[t] = ex;
    if (t == NBUCK - 1) bbase[NBUCK] = sh[t];
  }
}

// Pass A: scatter packed edges into bucket-contiguous pkB.
#define CHUNK 4096
__global__ __launch_bounds__(256) void bucket_scatter_kernel(
    const int* __restrict__ src, const int* __restrict__ dst,
    int* __restrict__ cbase, int* __restrict__ pkB, int E) {
  __shared__ int sS[CHUNK];
  __shared__ int dS[CHUNK];
  __shared__ int cnt[512];
  __shared__ int base[512];
  const int t = threadIdx.x;
  const int e0 = blockIdx.x * CHUNK;
  const int n = min(CHUNK, E - e0);
  for (int i = t; i < 512; i += 256) cnt[i] = 0;
  for (int i = t; i < n; i += 256) {
    sS[i] = src[e0 + i];
    dS[i] = dst[e0 + i];
  }
  __syncthreads();
  for (int i = t; i < n; i += 256) atomicAdd(&cnt[dS[i] >> BSHIFT], 1);
  __syncthreads();
  for (int i = t; i < 512; i += 256) {
    int c = cnt[i];
    base[i] = c ? atomicAdd(&cbase[i], c) : 0;
  }
  __syncthreads();
  for (int i = t; i < 512; i += 256) cnt[i] = 0;
  __syncthreads();
  for (int i = t; i < n; i += 256) {
    int d = dS[i];
    int b = d >> BSHIFT;
    int r = atomicAdd(&cnt[b], 1);
    pkB[base[b] + r] = ((d & BMASK) << 20) | sS[i];
  }
}

// Fused per-bucket finalize: LDS deg-hist -> LDS scan -> off/dinv/cursor ->
// CSR scatter. One block per bucket.
__global__ __launch_bounds__(256) void bucket_finalize_kernel(
    const int* __restrict__ pkB, const int* __restrict__ bbase,
    int* __restrict__ off, float* __restrict__ dinv, int* __restrict__ srcS,
    int N) {
  __shared__ int cnt[256];
  __shared__ int sh[256];
  const int t = threadIdx.x;
  const int b = blockIdx.x;
  const int lo = bbase[b], hi = bbase[b + 1];
  cnt[t] = 0;
  __syncthreads();
  for (int i = lo + t; i < hi; i += 256) atomicAdd(&cnt[pkB[i] >> 20], 1);
  __syncthreads();
  const int deg = cnt[t];
  sh[t] = deg;
  __syncthreads();
  for (int o = 1; o < 256; o <<= 1) {
    int a = (t >= o) ? sh[t - o] : 0;
    __syncthreads();
    sh[t] += a;
    __syncthreads();
  }
  const int ex = sh[t] - deg;  // exclusive prefix within bucket
  const int node = (b << BSHIFT) + t;
  if (node < N) {
    off[node] = lo + ex;
    dinv[node] = 1.0f / sqrtf((float)deg + 2.0f);
    if (node == N - 1) off[N] = hi;
  }
  cnt[t] = lo + ex;  // cursor
  __syncthreads();
  for (int i = lo + t; i < hi; i += 256) {
    int u = pkB[i];
    int pos = atomicAdd(&cnt[u >> 20], 1);
    srcS[pos] = u & 0xFFFFF;
  }
}

// ------------------------- per-node gather (shared) -------------------------
// Lane layout: g = lane>>4 (edge group 0..3), fq = lane&15 (float4 chunk).
// Masked 16-edge loop; after merge, g==0 lanes hold the relu'd result row
// chunk. Math identical to round-9 aggregate (bitwise-stable).
__device__ __forceinline__ float4 gather_node_row(
    const float4* __restrict__ xw4, const int* __restrict__ srcS,
    const float* __restrict__ dinv, const float* __restrict__ bias,
    int node, int beg, int end, int g, int fq) {
  float4 a0 = make_float4(0.f, 0.f, 0.f, 0.f);
  float4 a1 = a0, a2 = a0, a3 = a0;
  for (int e = beg; e < end; e += 16) {
    int e0 = e + g, e1 = e + 4 + g, e2 = e + 8 + g, e3 = e + 12 + g;
    int s0 = srcS[min(e0, end - 1)];
    int s1 = srcS[min(e1, end - 1)];
    int s2 = srcS[min(e2, end - 1)];
    int s3 = srcS[min(e3, end - 1)];
    float4 v0 = xw4[(size_t)s0 * 16 + fq];
    float4 v1 = xw4[(size_t)s1 * 16 + fq];
    float4 v2 = xw4[(size_t)s2 * 16 + fq];
    float4 v3 = xw4[(size_t)s3 * 16 + fq];
    if (e0 < end) { a0.x += v0.x; a0.y += v0.y; a0.z += v0.z; a0.w += v0.w; }
    if (e1 < end) { a1.x += v1.x; a1.y += v1.y; a1.z += v1.z; a1.w += v1.w; }
    if (e2 < end) { a2.x += v2.x; a2.y += v2.y; a2.z += v2.z; a2.w += v2.w; }
    if (e3 < end) { a3.x += v3.x; a3.y += v3.y; a3.z += v3.z; a3.w += v3.w; }
  }
  float4 a;
  a.x = (a0.x + a1.x) + (a2.x + a3.x);
  a.y = (a0.y + a1.y) + (a2.y + a3.y);
  a.z = (a0.z + a1.z) + (a2.z + a3.z);
  a.w = (a0.w + a1.w) + (a2.w + a3.w);
  a.x += __shfl_xor(a.x, 16, 64); a.x += __shfl_xor(a.x, 32, 64);
  a.y += __shfl_xor(a.y, 16, 64); a.y += __shfl_xor(a.y, 32, 64);
  a.z += __shfl_xor(a.z, 16, 64); a.z += __shfl_xor(a.z, 32, 64);
  a.w += __shfl_xor(a.w, 16, 64); a.w += __shfl_xor(a.w, 32, 64);
  float di = dinv[node];
  float4 self = xw4[(size_t)node * 16 + fq];
  float4 b = ((const float4*)bias)[fq];
  float4 r;
  r.x = fmaxf(di * (a.x + 2.0f * self.x) + b.x, 0.f);
  r.y = fmaxf(di * (a.y + 2.0f * self.y) + b.y, 0.f);
  r.z = fmaxf(di * (a.z + 2.0f * self.z) + b.z, 0.f);
  r.w = fmaxf(di * (a.w + 2.0f * self.w) + b.w, 0.f);
  return r;
}

// ------------------------------- GEMM (K1) ----------------------------------
// Y[64-row tile] = dinv[row] * (X(64 cols) @ W(64 x 64)), float4 epilogue.
__global__ __launch_bounds__(256) void gemm64v2_kernel(
    const float* __restrict__ X, const float* __restrict__ W,
    const float* __restrict__ dinv, float* __restrict__ Y, int N) {
  __shared__ float Ws[64 * 64];
  __shared__ float Xs[64 * 68];
  const int t = threadIdx.x;
  {
    const float4* W4 = (const float4*)W;
    float4* Ws4 = (float4*)Ws;
    for (int i = t; i < 16 * 64; i += 256) Ws4[i] = W4[i];
  }
  const int row0 = blockIdx.x * 64;
  for (int i = t; i < 64 * 16; i += 256) {
    int r = i >> 4, c4 = i & 15;
    int gr = row0 + r;
    float4 v = make_float4(0.f, 0.f, 0.f, 0.f);
    if (gr < N) v = *(const float4*)&X[(size_t)gr * 64 + c4 * 4];
    *(float4*)&Xs[r * 68 + c4 * 4] = v;
  }
  __syncthreads();

  const int tx = t & 15, ty = t >> 4;
  const int c0 = tx * 4;
  const int r0 = ty * 4;
  float acc[4][4];
#pragma unroll
  for (int i = 0; i < 4; ++i)
#pragma unroll
    for (int j = 0; j < 4; ++j) acc[i][j] = 0.f;

#pragma unroll 4
  for (int k4 = 0; k4 < 16; ++k4) {
    float4 xv[4];
#pragma unroll
    for (int i = 0; i < 4; ++i)
      xv[i] = *(const float4*)&Xs[(r0 + i) * 68 + k4 * 4];
#pragma unroll
    for (int kk = 0; kk < 4; ++kk) {
      float w[4];
#pragma unroll
      for (int j = 0; j < 4; ++j) w[j] = Ws[(k4 * 4 + kk) * 64 + c0 + j];
      const float xk[4] = {
          kk == 0 ? xv[0].x : kk == 1 ? xv[0].y : kk == 2 ? xv[0].z : xv[0].w,
          kk == 0 ? xv[1].x : kk == 1 ? xv[1].y : kk == 2 ? xv[1].z : xv[1].w,
          kk == 0 ? xv[2].x : kk == 1 ? xv[2].y : kk == 2 ? xv[2].z : xv[2].w,
          kk == 0 ? xv[3].x : kk == 1 ? xv[3].y : kk == 2 ? xv[3].z : xv[3].w};
#pragma unroll
      for (int i = 0; i < 4; ++i)
#pragma unroll
        for (int j = 0; j < 4; ++j) acc[i][j] = fmaf(xk[i], w[j], acc[i][j]);
    }
  }

#pragma unroll
  for (int i = 0; i < 4; ++i) {
    int gr = row0 + r0 + i;
    if (gr >= N) continue;
    float sc = dinv[gr];
    float4 v = make_float4(acc[i][0] * sc, acc[i][1] * sc, acc[i][2] * sc,
                           acc[i][3] * sc);
    *(float4*)&Y[(size_t)gr * 64 + c0] = v;
  }
}

// ------------------------- K2: agg1 -> LDS -> gemm2 -------------------------
// Phase A: each of 4 waves gathers 16 of the tile's 64 nodes; h1 rows land in
// LDS Xs (pad 68, same layout gemm reads). Phase B: gemm body on LDS tile,
// epilogue scales by dinv and stores xws2 to global. h1 never touches HBM.
__global__ __launch_bounds__(256) void agg_gemm_kernel(
    const float* __restrict__ xws, const int* __restrict__ srcS,
    const int* __restrict__ off, const float* __restrict__ dinv,
    const float* __restrict__ bias, const float* __restrict__ W,
    float* __restrict__ Y, int N) {
  __shared__ float Xs[64 * 68];
  __shared__ float Ws[64 * 64];
  const int t = threadIdx.x;
  const int row0 = blockIdx.x * 64;
  const int wave = t >> 6, lane = t & 63;
  const int g = lane >> 4, fq = lane & 15;

  // stage Ws (coalesced) — consumed after the barrier
  {
    const float4* W4 = (const float4*)W;
    float4* Ws4 = (float4*)Ws;
    for (int i = t; i < 1024; i += 256) Ws4[i] = W4[i];
  }
  // Phase A: aggregate h1 rows into Xs
  const float4* xw4 = (const float4*)xws;
  for (int idx = wave; idx < 64; idx += 4) {
    int node = row0 + idx;
    if (node >= N) continue;
    int beg = off[node], end = off[node + 1];
    float4 r = gather_node_row(xw4, srcS, dinv, bias, node, beg, end, g, fq);
    if (g == 0) *(float4*)&Xs[idx * 68 + fq * 4] = r;
  }
  __syncthreads();

  // Phase B: gemm (identical body to gemm64v2)
  const int tx = t & 15, ty = t >> 4;
  const int c0 = tx * 4;
  const int r0 = ty * 4;
  float acc[4][4];
#pragma unroll
  for (int i = 0; i < 4; ++i)
#pragma unroll
    for (int j = 0; j < 4; ++j) acc[i][j] = 0.f;

#pragma unroll 4
  for (int k4 = 0; k4 < 16; ++k4) {
    float4 xv[4];
#pragma unroll
    for (int i = 0; i < 4; ++i)
      xv[i] = *(const float4*)&Xs[(r0 + i) * 68 + k4 * 4];
#pragma unroll
    for (int kk = 0; kk < 4; ++kk) {
      float w[4];
#pragma unroll
      for (int j = 0; j < 4; ++j) w[j] = Ws[(k4 * 4 + kk) * 64 + c0 + j];
      const float xk[4] = {
          kk == 0 ? xv[0].x : kk == 1 ? xv[0].y : kk == 2 ? xv[0].z : xv[0].w,
          kk == 0 ? xv[1].x : kk == 1 ? xv[1].y : kk == 2 ? xv[1].z : xv[1].w,
          kk == 0 ? xv[2].x : kk == 1 ? xv[2].y : kk == 2 ? xv[2].z : xv[2].w,
          kk == 0 ? xv[3].x : kk == 1 ? xv[3].y : kk == 2 ? xv[3].z : xv[3].w};
#pragma unroll
      for (int i = 0; i < 4; ++i)
#pragma unroll
        for (int j = 0; j < 4; ++j) acc[i][j] = fmaf(xk[i], w[j], acc[i][j]);
    }
  }

#pragma unroll
  for (int i = 0; i < 4; ++i) {
    int gr = row0 + r0 + i;
    if (gr >= N) continue;
    float sc = dinv[gr];
    float4 v = make_float4(acc[i][0] * sc, acc[i][1] * sc, acc[i][2] * sc,
                           acc[i][3] * sc);
    *(float4*)&Y[(size_t)gr * 64 + c0] = v;
  }
}

// ------------------------- K3: agg2 -> LDS -> head --------------------------
// Phase A: stage rep tile (swizzled cols 0..63) + aggregate h2 rows directly
// into the swizzled upper half of Xs (cols 64..127). Phase B: head with
// b128 quad-k x-reads (conflict-free: 4 ty-groups hit 4 distinct bank quads;
// W reads stride-4 = free 2-way). FMA k-order strictly ascending.
__global__ __launch_bounds__(256) void agg_head_kernel(
    const float* __restrict__ xws2, const int* __restrict__ srcS,
    const int* __restrict__ off, const float* __restrict__ dinv,
    const float* __restrict__ b2, const float* __restrict__ rep,
    const float* __restrict__ Wa, const float* __restrict__ ba,
    const float* __restrict__ Wb, const float* __restrict__ bb,
    const float* __restrict__ Wo, const float* __restrict__ bo,
    float* __restrict__ out, int N) {
  __shared__ float Xs[64 * 128];    // 32 KB swizzled ([rep,h2]; later zaS)
  __shared__ float Wbuf[32 * 128];  // 16 KB weight staging; later reduction
  const int t = threadIdx.x;
  const int row0 = blockIdx.x * 64;
  const int wave = t >> 6, lane = t & 63;
  const int g = lane >> 4, fq = lane & 15;

  // stage rep tile (cols 0..63), swizzled, coalesced float4
  for (int i = t; i < 1024; i += 256) {
    int r = i >> 4, c4 = i & 15;
    int gr = row0 + r;
    float4 v = make_float4(0.f, 0.f, 0.f, 0.f);
    if (gr < N) v = *(const float4*)&rep[(size_t)gr * 64 + c4 * 4];
    int scol = (c4 * 4 + ((r >> 2) << 2)) & 127;
    *(float4*)&Xs[r * 128 + scol] = v;
  }
  // aggregate h2 rows into swizzled cols 64..127
  const float4* xw4 = (const float4*)xws2;
  for (int idx = wave; idx < 64; idx += 4) {
    int node = row0 + idx;
    if (node >= N) continue;
    int beg = off[node], end = off[node + 1];
    float4 r = gather_node_row(xw4, srcS, dinv, b2, node, beg, end, g, fq);
    if (g == 0) {
      int scol = ((64 + fq * 4) + ((idx >> 2) << 2)) & 127;
      *(float4*)&Xs[idx * 128 + scol] = r;
    }
  }

  const int tx = t & 15, ty = t >> 4;
  const int cL = tx * 4;        // low-half za cols
  const int cH = 64 + tx * 4;   // high-half za cols
  const int r0 = ty * 4;        // rows; (r0+i)>>2 == ty
  float za[4][8];
#pragma unroll
  for (int i = 0; i < 4; ++i)
#pragma unroll
    for (int j = 0; j < 8; ++j) za[i][j] = 0.f;

  // za accumulation: K=128 in four 32-row chunks of Wa (16KB LDS-staged)
  for (int chunk = 0; chunk < 4; ++chunk) {
    __syncthreads();
    const float4* Wa4 = (const float4*)(Wa + chunk * 32 * 128);
    float4* Wd = (float4*)Wbuf;
    for (int i = t; i < 1024; i += 256) Wd[i] = Wa4[i];
    __syncthreads();
    const int kb = chunk * 32;
    for (int k4 = 0; k4 < 8; ++k4) {
      const int kc = (kb + k4 * 4 + (ty << 2)) & 127;  // aligned quad
      float4 xq[4];
#pragma unroll
      for (int i = 0; i < 4; ++i)
        xq[i] = *(const float4*)&Xs[(r0 + i) * 128 + kc];
#pragma unroll
      for (int sub = 0; sub < 4; ++sub) {
        const int kk = k4 * 4 + sub;
        float4 w0 = *(const float4*)&Wbuf[kk * 128 + cL];  // stride-4: free
        float4 w1 = *(const float4*)&Wbuf[kk * 128 + cH];  // stride-4: free
        const float w[8] = {w0.x, w0.y, w0.z, w0.w, w1.x, w1.y, w1.z, w1.w};
#pragma unroll
        for (int i = 0; i < 4; ++i) {
          float x = sub == 0 ? xq[i].x : sub == 1 ? xq[i].y
                  : sub == 2 ? xq[i].z : xq[i].w;
#pragma unroll
          for (int j = 0; j < 8; ++j) za[i][j] = fmaf(x, w[j], za[i][j]);
        }
      }
    }
  }
  // bias + relu (cols cL+j for j<4, cH+j-4 for j>=4)
#pragma unroll
  for (int i = 0; i < 4; ++i) {
#pragma unroll
    for (int j = 0; j < 4; ++j) {
      za[i][j] = fmaxf(za[i][j] + ba[cL + j], 0.f);
      za[i][4 + j] = fmaxf(za[i][4 + j] + ba[cH + j], 0.f);
    }
  }

  // write za into LDS (Xs region is dead now), same swizzle
  __syncthreads();
  float* zaS = Xs;
  {
    int sL = (cL + (ty << 2)) & 127;
    int sH = (cH + (ty << 2)) & 127;
#pragma unroll
    for (int i = 0; i < 4; ++i) {
      *(float4*)&zaS[(r0 + i) * 128 + sL] =
          make_float4(za[i][0], za[i][1], za[i][2], za[i][3]);
      *(float4*)&zaS[(r0 + i) * 128 + sH] =
          make_float4(za[i][4], za[i][5], za[i][6], za[i][7]);
    }
  }

  const int c0b = tx * 4;  // zb cols (M2=64)
  float zb[4][4];
#pragma unroll
  for (int i = 0; i < 4; ++i)
#pragma unroll
    for (int j = 0; j < 4; ++j) zb[i][j] = 0.f;

  // zb accumulation: K=128 in two 64-row chunks of Wb (16KB LDS-staged)
  for (int chunk = 0; chunk < 2; ++chunk) {
    __syncthreads();
    const float4* Wb4 = (const float4*)(Wb + chunk * 64 * 64);
    float4* Wd = (float4*)Wbuf;
    for (int i = t; i < 1024; i += 256) Wd[i] = Wb4[i];
    __syncthreads();
    const int kb = chunk * 64;
    for (int k4 = 0; k4 < 16; ++k4) {
      const int kc = (kb + k4 * 4 + (ty << 2)) & 127;
      float4 xq[4];
#pragma unroll
      for (int i = 0; i < 4; ++i)
        xq[i] = *(const float4*)&zaS[(r0 + i) * 128 + kc];
#pragma unroll
      for (int sub = 0; sub < 4; ++sub) {
        const int kk = k4 * 4 + sub;
        float4 w = *(const float4*)&Wbuf[kk * 64 + c0b];  // stride-4: free
        const float wj[4] = {w.x, w.y, w.z, w.w};
#pragma unroll
        for (int i = 0; i < 4; ++i) {
          float x = sub == 0 ? xq[i].x : sub == 1 ? xq[i].y
                  : sub == 2 ? xq[i].z : xq[i].w;
#pragma unroll
          for (int j = 0; j < 4; ++j) zb[i][j] = fmaf(x, wj[j], zb[i][j]);
        }
      }
    }
  }
  // bias + relu + partial Wo dot
  float part[4];
#pragma unroll
  for (int i = 0; i < 4; ++i) {
    part[i] = 0.f;
#pragma unroll
    for (int j = 0; j < 4; ++j) {
      float v = fmaxf(zb[i][j] + bb[c0b + j], 0.f);
      part[i] = fmaf(v, Wo[c0b + j], part[i]);
    }
  }
  // reduce 16 partials per row via LDS (Wbuf is dead now)
  __syncthreads();
  float* red = Wbuf;
#pragma unroll
  for (int i = 0; i < 4; ++i) red[tx * 68 + r0 + i] = part[i];
  __syncthreads();
  if (t < 64) {
    int gr = row0 + t;
    if (gr < N) {
      float s = 0.f;
#pragma unroll
      for (int u = 0; u < 16; ++u) s += red[u * 68 + t];
      float w = s + bo[0];
      float p = 1.0f / (1.0f + expf(-w));
      unsigned i = (unsigned)gr;
      unsigned bits0 = jax_random_bits_u32(0u, 42u, 2u * i);
      unsigned bits1 = jax_random_bits_u32(0u, 42u, 2u * i + 1u);
      float f0 = __uint_as_float((bits0 >> 9) | 0x3f800000u) - 1.0f;
      float f1 = __uint_as_float((bits1 >> 9) | 0x3f800000u) - 1.0f;
      float u0 = fmaxf(1e-20f, f0 + 1e-20f);
      float u1 = fmaxf(1e-20f, f1 + 1e-20f);
      float g0 = -logf(-logf(u0));
      float g1 = -logf(-logf(u1));
      float a0 = (1.0f - p) + g0;
      float a1 = p + g1;
      float m = fmaxf(a0, a1);
      float e0 = expf(a0 - m), e1 = expf(a1 - m);
      float ssum = e0 + e1;
      float y0 = e0 / ssum, y1 = e1 / ssum;
      float hard1 = (y1 > y0) ? 1.0f : 0.0f;
      float st1 = (hard1 + y1) - y1;
      out[gr] = p;
      out[N + gr] = st1;
    }
  }
}

// ------------------------------- launcher ----------------------------------
extern "C" void kernel_launch(void* const* d_in, const int* in_sizes, int n_in,
                              void* d_out, int out_size, void* d_ws, size_t ws_size,
                              hipStream_t stream) {
  const float* rep = (const float*)d_in[0];
  const int* ei = (const int*)d_in[1];
  const float* W1 = (const float*)d_in[2];
  const float* b1 = (const float*)d_in[3];
  const float* W2 = (const float*)d_in[4];
  const float* b2 = (const float*)d_in[5];
  const float* Wa = (const float*)d_in[6];
  const float* ba = (const float*)d_in[7];
  const float* Wb = (const float*)d_in[8];
  const float* bb = (const float*)d_in[9];
  const float* Wo = (const float*)d_in[10];
  const float* bo = (const float*)d_in[11];
  float* out = (float*)d_out;

  const int N = in_sizes[0] / 64;   // < 2^20 (packing requirement)
  const int E = in_sizes[1] / 2;
  const int* srcI = ei;      // edge_index[0]
  const int* dstI = ei + E;  // edge_index[1]

  const int NBUCK = (N + 255) >> BSHIFT;  // <= 512

  // workspace layout
  float* ws = (float*)d_ws;
  float* bufA = ws;                          // N*64 (xws1)
  float* bufB = bufA + (size_t)N * 64;       // N*64 (xws2)
  float* dinv = bufB + (size_t)N * 64;       // N
  int* coarse = (int*)(dinv + N);            // 512
  int* bbase = coarse + 512;                 // 513
  int* cbase = bbase + 513;                  // 512
  int* off = cbase + 512;                    // N+1
  int* pkB = off + N + 1;                    // E (packed bucketed edges)
  int* srcS = pkB + E;                       // E (CSR src list)

  const int nb64 = (N + 63) / 64;
  const int nbA = (E + CHUNK - 1) / CHUNK;

  // ---- bucketed CSR build + dinv
  hipMemsetAsync(coarse, 0, 512 * 4, stream);
  coarse_hist_kernel<<<256, 256, 0, stream>>>(dstI, coarse, E);
  coarse_scan_kernel<<<1, 512, 0, stream>>>(coarse, bbase, cbase, NBUCK);
  bucket_scatter_kernel<<<nbA, 256, 0, stream>>>(srcI, dstI, cbase, pkB, E);
  bucket_finalize_kernel<<<NBUCK, 256, 0, stream>>>(pkB, bbase, off, dinv,
                                                    srcS, N);

  // ---- K1: xws1 = dinv * (rep @ W1)
  gemm64v2_kernel<<<nb64, 256, 0, stream>>>(rep, W1, dinv, bufA, N);

  // ---- K2: agg1 (h1 in LDS) -> xws2 = dinv * (h1 @ W2)
  agg_gemm_kernel<<<nb64, 256, 0, stream>>>(bufA, srcS, off, dinv, b1, W2,
                                            bufB, N);

  // ---- K3: agg2 (h2 in LDS) -> head -> prob + gumbel indicator
  agg_head_kernel<<<nb64, 256, 0, stream>>>(bufB, srcS, off, dinv, b2, rep,
                                            Wa, ba, Wb, bb, Wo, bo, out, N);
}

// Round 11
// 397.615 us; speedup vs baseline: 1.3414x; 1.3414x over previous
//
#include <hip/hip_runtime.h>
#include <math.h>

// ---------------------------------------------------------------------------
// GraphNewPolicyNetwork: 2x GCNConv(improved=True) + MLP head + sigmoid +
// gumbel-softmax(hard) straight-through indicator.
// N=100000 nodes, E=1600000 edges, D=H1=H2=64, M1=128, M2=64.
// Outputs: d_out[0:N] = prob (f32), d_out[N:2N] = ind (f32, 0/1).
//
// Round 11: revert round-10 fusion (it cut gather warps 16x -> 391->533 us).
// Round-9 structure (separate gemm/aggregate/head) + head za/zb x-reads in
// quad-k b128 form (verified bitwise + conflict-free inside round 10).
// ---------------------------------------------------------------------------

// ----------------------------- threefry2x32 --------------------------------
__device__ __forceinline__ unsigned rotl32(unsigned x, int r) {
  return (x << r) | (x >> (32 - r));
}

// JAX threefry2x32 (20 rounds), matches jax/_src/prng.py
__device__ __forceinline__ void threefry2x32(unsigned k0, unsigned k1,
                                             unsigned x0, unsigned x1,
                                             unsigned& o0, unsigned& o1) {
  unsigned ks2 = k0 ^ k1 ^ 0x1BD11BDAu;
#define TF_RND(r) { x0 += x1; x1 = rotl32(x1, (r)); x1 ^= x0; }
  x0 += k0; x1 += k1;
  TF_RND(13) TF_RND(15) TF_RND(26) TF_RND(6)
  x0 += k1; x1 += ks2 + 1u;
  TF_RND(17) TF_RND(29) TF_RND(16) TF_RND(24)
  x0 += ks2; x1 += k0 + 2u;
  TF_RND(13) TF_RND(15) TF_RND(26) TF_RND(6)
  x0 += k0; x1 += k1 + 3u;
  TF_RND(17) TF_RND(29) TF_RND(16) TF_RND(24)
  x0 += k1; x1 += ks2 + 4u;
  TF_RND(13) TF_RND(15) TF_RND(26) TF_RND(6)
  x0 += ks2; x1 += k0 + 5u;
#undef TF_RND
  o0 = x0; o1 = x1;
}

// Partitionable threefry bits: element flat index j -> counter (0, j),
// 32-bit output = out0 ^ out1.
__device__ __forceinline__ unsigned jax_random_bits_u32(unsigned k0, unsigned k1,
                                                        unsigned flat_idx) {
  unsigned a, b;
  threefry2x32(k0, k1, 0u, flat_idx, a, b);
  return a ^ b;
}

// --------------------------- bucketed CSR build ----------------------------
// bucket(d) = d >> 8  (256 nodes per bucket, NBUCK = ceil(N/256) <= 512).
// Packed edge: (dlocal << 20) | src   (requires src < 2^20, dlocal < 2^12).
#define BSHIFT 8
#define BMASK 255

// Per-block LDS histogram of buckets, merged into global coarse[].
__global__ __launch_bounds__(256) void coarse_hist_kernel(
    const int* __restrict__ dst, int* __restrict__ coarse, int E) {
  __shared__ int h[512];
  for (int i = threadIdx.x; i < 512; i += 256) h[i] = 0;
  __syncthreads();
  for (int e = blockIdx.x * blockDim.x + threadIdx.x; e < E;
       e += gridDim.x * blockDim.x)
    atomicAdd(&h[dst[e] >> BSHIFT], 1);
  __syncthreads();
  for (int i = threadIdx.x; i < 512; i += 256)
    if (h[i]) atomicAdd(&coarse[i], h[i]);
}

// Single block: exclusive scan of coarse -> bbase (bucket ranges) and cbase
// (scatter cursors).
__global__ __launch_bounds__(512) void coarse_scan_kernel(
    const int* __restrict__ coarse, int* __restrict__ bbase,
    int* __restrict__ cbase, int NBUCK) {
  __shared__ int sh[512];
  int t = threadIdx.x;
  int v = (t < NBUCK) ? coarse[t] : 0;
  sh[t] = v;
  __syncthreads();
  for (int o = 1; o < 512; o <<= 1) {
    int a = (t >= o) ? sh[t - o] : 0;
    __syncthreads();
    sh[t] += a;
    __syncthreads();
  }
  if (t < NBUCK) {
    int ex = sh[t] - v;
    bbase[t] = ex;
    cbase[t] = ex;
    if (t == NBUCK - 1) bbase[NBUCK] = sh[t];
  }
}

// Pass A: scatter packed edges into bucket-contiguous pkB.
#define CHUNK 4096
__global__ __launch_bounds__(256) void bucket_scatter_kernel(
    const int* __restrict__ src, const int* __restrict__ dst,
    int* __restrict__ cbase, int* __restrict__ pkB, int E) {
  __shared__ int sS[CHUNK];
  __shared__ int dS[CHUNK];
  __shared__ int cnt[512];
  __shared__ int base[512];
  const int t = threadIdx.x;
  const int e0 = blockIdx.x * CHUNK;
  const int n = min(CHUNK, E - e0);
  for (int i = t; i < 512; i += 256) cnt[i] = 0;
  for (int i = t; i < n; i += 256) {
    sS[i] = src[e0 + i];
    dS[i] = dst[e0 + i];
  }
  __syncthreads();
  for (int i = t; i < n; i += 256) atomicAdd(&cnt[dS[i] >> BSHIFT], 1);
  __syncthreads();
  for (int i = t; i < 512; i += 256) {
    int c = cnt[i];
    base[i] = c ? atomicAdd(&cbase[i], c) : 0;
  }
  __syncthreads();
  for (int i = t; i < 512; i += 256) cnt[i] = 0;
  __syncthreads();
  for (int i = t; i < n; i += 256) {
    int d = dS[i];
    int b = d >> BSHIFT;
    int r = atomicAdd(&cnt[b], 1);
    pkB[base[b] + r] = ((d & BMASK) << 20) | sS[i];
  }
}

// Fused per-bucket finalize: LDS deg-hist -> LDS scan -> off/dinv/cursor ->
// CSR scatter. One block per bucket.
__global__ __launch_bounds__(256) void bucket_finalize_kernel(
    const int* __restrict__ pkB, const int* __restrict__ bbase,
    int* __restrict__ off, float* __restrict__ dinv, int* __restrict__ srcS,
    int N) {
  __shared__ int cnt[256];
  __shared__ int sh[256];
  const int t = threadIdx.x;
  const int b = blockIdx.x;
  const int lo = bbase[b], hi = bbase[b + 1];
  cnt[t] = 0;
  __syncthreads();
  for (int i = lo + t; i < hi; i += 256) atomicAdd(&cnt[pkB[i] >> 20], 1);
  __syncthreads();
  const int deg = cnt[t];
  sh[t] = deg;
  __syncthreads();
  for (int o = 1; o < 256; o <<= 1) {
    int a = (t >= o) ? sh[t - o] : 0;
    __syncthreads();
    sh[t] += a;
    __syncthreads();
  }
  const int ex = sh[t] - deg;  // exclusive prefix within bucket
  const int node = (b << BSHIFT) + t;
  if (node < N) {
    off[node] = lo + ex;
    dinv[node] = 1.0f / sqrtf((float)deg + 2.0f);
    if (node == N - 1) off[N] = hi;
  }
  cnt[t] = lo + ex;  // cursor
  __syncthreads();
  for (int i = lo + t; i < hi; i += 256) {
    int u = pkB[i];
    int pos = atomicAdd(&cnt[u >> 20], 1);
    srcS[pos] = u & 0xFFFFF;
  }
}

// ---------------------------- aggregation ----------------------------------
// One wave per dst node. Lane layout: g = lane>>4 (edge group 0..3),
// fq = lane&15 (float4 chunk of the 64-f row). Masked 16-edge loop: all 4
// gathers stay in flight even for the tail.
// h[d] = relu(dinv[d]*(sum_{e in CSR[d]} xws[src] + 2*xws[d]) + bias)
__global__ __launch_bounds__(256) void aggregate_kernel(
    const float* __restrict__ xws, const int* __restrict__ srcS,
    const int* __restrict__ off, const float* __restrict__ dinv,
    const float* __restrict__ bias, float* __restrict__ h, int N) {
  int node = (blockIdx.x * blockDim.x + threadIdx.x) >> 6;
  int lane = threadIdx.x & 63;
  int g = lane >> 4;   // edge group
  int fq = lane & 15;  // float4 index within row
  if (node >= N) return;
  const float4* xw4 = (const float4*)xws;  // row stride = 16 float4
  int beg = off[node], end = off[node + 1];
  float4 a0 = make_float4(0.f, 0.f, 0.f, 0.f);
  float4 a1 = a0, a2 = a0, a3 = a0;
  for (int e = beg; e < end; e += 16) {
    int e0 = e + g, e1 = e + 4 + g, e2 = e + 8 + g, e3 = e + 12 + g;
    int s0 = srcS[min(e0, end - 1)];
    int s1 = srcS[min(e1, end - 1)];
    int s2 = srcS[min(e2, end - 1)];
    int s3 = srcS[min(e3, end - 1)];
    float4 v0 = xw4[(size_t)s0 * 16 + fq];
    float4 v1 = xw4[(size_t)s1 * 16 + fq];
    float4 v2 = xw4[(size_t)s2 * 16 + fq];
    float4 v3 = xw4[(size_t)s3 * 16 + fq];
    if (e0 < end) { a0.x += v0.x; a0.y += v0.y; a0.z += v0.z; a0.w += v0.w; }
    if (e1 < end) { a1.x += v1.x; a1.y += v1.y; a1.z += v1.z; a1.w += v1.w; }
    if (e2 < end) { a2.x += v2.x; a2.y += v2.y; a2.z += v2.z; a2.w += v2.w; }
    if (e3 < end) { a3.x += v3.x; a3.y += v3.y; a3.z += v3.z; a3.w += v3.w; }
  }
  float4 a;
  a.x = (a0.x + a1.x) + (a2.x + a3.x);
  a.y = (a0.y + a1.y) + (a2.y + a3.y);
  a.z = (a0.z + a1.z) + (a2.z + a3.z);
  a.w = (a0.w + a1.w) + (a2.w + a3.w);
  // merge the 4 edge groups (lanes fq, 16+fq, 32+fq, 48+fq)
  a.x += __shfl_xor(a.x, 16, 64); a.x += __shfl_xor(a.x, 32, 64);
  a.y += __shfl_xor(a.y, 16, 64); a.y += __shfl_xor(a.y, 32, 64);
  a.z += __shfl_xor(a.z, 16, 64); a.z += __shfl_xor(a.z, 32, 64);
  a.w += __shfl_xor(a.w, 16, 64); a.w += __shfl_xor(a.w, 32, 64);
  if (g == 0) {
    float di = dinv[node];
    float4 self = xw4[(size_t)node * 16 + fq];
    float4 b = ((const float4*)bias)[fq];
    float4 r;
    r.x = fmaxf(di * (a.x + 2.0f * self.x) + b.x, 0.f);
    r.y = fmaxf(di * (a.y + 2.0f * self.y) + b.y, 0.f);
    r.z = fmaxf(di * (a.z + 2.0f * self.z) + b.z, 0.f);
    r.w = fmaxf(di * (a.w + 2.0f * self.w) + b.w, 0.f);
    *(float4*)&h[(size_t)node * 64 + fq * 4] = r;
  }
}

// ------------------------------- GEMM --------------------------------------
// Y[64-row tile] = X(64 cols) @ W(64 x 64), register-tiled, float4 epilogue.
// Xs rows padded to 68: ty-group b128 reads land on distinct bank quads.
// flags: 8 = scale result by dinv[row]
__global__ __launch_bounds__(256) void gemm64v2_kernel(
    const float* __restrict__ X, const float* __restrict__ W,
    const float* __restrict__ dinv, float* __restrict__ Y, int N, int flags) {
  __shared__ float Ws[64 * 64];
  __shared__ float Xs[64 * 68];
  const int t = threadIdx.x;
  {
    const float4* W4 = (const float4*)W;
    float4* Ws4 = (float4*)Ws;
    for (int i = t; i < 16 * 64; i += 256) Ws4[i] = W4[i];
  }
  const int row0 = blockIdx.x * 64;
  for (int i = t; i < 64 * 16; i += 256) {
    int r = i >> 4, c4 = i & 15;
    int gr = row0 + r;
    float4 v = make_float4(0.f, 0.f, 0.f, 0.f);
    if (gr < N) v = *(const float4*)&X[(size_t)gr * 64 + c4 * 4];
    *(float4*)&Xs[r * 68 + c4 * 4] = v;
  }
  __syncthreads();

  const int tx = t & 15, ty = t >> 4;
  const int c0 = tx * 4;
  const int r0 = ty * 4;
  float acc[4][4];
#pragma unroll
  for (int i = 0; i < 4; ++i)
#pragma unroll
    for (int j = 0; j < 4; ++j) acc[i][j] = 0.f;

#pragma unroll 4
  for (int k4 = 0; k4 < 16; ++k4) {
    float4 xv[4];
#pragma unroll
    for (int i = 0; i < 4; ++i)
      xv[i] = *(const float4*)&Xs[(r0 + i) * 68 + k4 * 4];
#pragma unroll
    for (int kk = 0; kk < 4; ++kk) {
      float w[4];
#pragma unroll
      for (int j = 0; j < 4; ++j) w[j] = Ws[(k4 * 4 + kk) * 64 + c0 + j];
      const float xk[4] = {
          kk == 0 ? xv[0].x : kk == 1 ? xv[0].y : kk == 2 ? xv[0].z : xv[0].w,
          kk == 0 ? xv[1].x : kk == 1 ? xv[1].y : kk == 2 ? xv[1].z : xv[1].w,
          kk == 0 ? xv[2].x : kk == 1 ? xv[2].y : kk == 2 ? xv[2].z : xv[2].w,
          kk == 0 ? xv[3].x : kk == 1 ? xv[3].y : kk == 2 ? xv[3].z : xv[3].w};
#pragma unroll
      for (int i = 0; i < 4; ++i)
#pragma unroll
        for (int j = 0; j < 4; ++j) acc[i][j] = fmaf(xk[i], w[j], acc[i][j]);
    }
  }

#pragma unroll
  for (int i = 0; i < 4; ++i) {
    int gr = row0 + r0 + i;
    if (gr >= N) continue;
    float sc = (flags & 8) ? dinv[gr] : 1.0f;
    float4 v = make_float4(acc[i][0], acc[i][1], acc[i][2], acc[i][3]);
    if (flags & 8) { v.x *= sc; v.y *= sc; v.z *= sc; v.w *= sc; }
    *(float4*)&Y[(size_t)gr * 64 + c0] = v;
  }
}

// --------------------------- fused head kernel -----------------------------
// Per 64-row tile: za = relu([rep,h2]@Wa+ba); zb = relu(za@Wb+bb);
// p = sigmoid(zb@Wo+bo); gumbel straight-through.
// 256 threads, 4 rows x 8 cols/thread. Xs/zaS swizzle: (r,c) at
// r*128 + ((c + (r>>2)*4) & 127). x-reads are QUAD-K b128 (kc is a multiple
// of 4; the 4 ty-groups of a wave hit 4 distinct bank quads -> conflict-free,
// measured 0 in round 10). W cols split {tx*4, 64+tx*4} -> stride-4 b128
// (free 2-way). Wbuf 16KB chunked staging. LDS 48KB -> 3 blocks/CU.
// FMA k-order strictly ascending (bitwise-identical to rounds 6-10).
__global__ __launch_bounds__(256) void head_mega_kernel(
    const float* __restrict__ rep, const float* __restrict__ h2,
    const float* __restrict__ Wa, const float* __restrict__ ba,
    const float* __restrict__ Wb, const float* __restrict__ bb,
    const float* __restrict__ Wo, const float* __restrict__ bo,
    float* __restrict__ out, int N) {
  __shared__ float Xs[64 * 128];    // 32 KB swizzled ([rep,h2]; later zaS)
  __shared__ float Wbuf[32 * 128];  // 16 KB weight staging; later reduction
  const int t = threadIdx.x;
  const int row0 = blockIdx.x * 64;

  // stage [rep, h2] tile (64 x 128), swizzled, coalesced float4
  for (int i = t; i < 2048; i += 256) {
    int r = i >> 5, c4 = i & 31;
    int gr = row0 + r;
    float4 v = make_float4(0.f, 0.f, 0.f, 0.f);
    if (gr < N)
      v = (c4 < 16) ? *(const float4*)&rep[(size_t)gr * 64 + c4 * 4]
                    : *(const float4*)&h2[(size_t)gr * 64 + (c4 - 16) * 4];
    int scol = (c4 * 4 + ((r >> 2) << 2)) & 127;
    *(float4*)&Xs[r * 128 + scol] = v;
  }

  const int tx = t & 15, ty = t >> 4;
  const int cL = tx * 4;        // low-half za cols
  const int cH = 64 + tx * 4;   // high-half za cols
  const int r0 = ty * 4;        // rows; (r0+i)>>2 == ty
  float za[4][8];
#pragma unroll
  for (int i = 0; i < 4; ++i)
#pragma unroll
    for (int j = 0; j < 8; ++j) za[i][j] = 0.f;

  // za accumulation: K=128 in four 32-row chunks of Wa (16KB LDS-staged)
  for (int chunk = 0; chunk < 4; ++chunk) {
    __syncthreads();
    const float4* Wa4 = (const float4*)(Wa + chunk * 32 * 128);
    float4* Wd = (float4*)Wbuf;
    for (int i = t; i < 1024; i += 256) Wd[i] = Wa4[i];
    __syncthreads();
    const int kb = chunk * 32;
    for (int k4 = 0; k4 < 8; ++k4) {
      const int kc = (kb + k4 * 4 + (ty << 2)) & 127;  // aligned quad
      float4 xq[4];
#pragma unroll
      for (int i = 0; i < 4; ++i)
        xq[i] = *(const float4*)&Xs[(r0 + i) * 128 + kc];
#pragma unroll
      for (int sub = 0; sub < 4; ++sub) {
        const int kk = k4 * 4 + sub;
        float4 w0 = *(const float4*)&Wbuf[kk * 128 + cL];  // stride-4: free
        float4 w1 = *(const float4*)&Wbuf[kk * 128 + cH];  // stride-4: free
        const float w[8] = {w0.x, w0.y, w0.z, w0.w, w1.x, w1.y, w1.z, w1.w};
#pragma unroll
        for (int i = 0; i < 4; ++i) {
          float x = sub == 0 ? xq[i].x : sub == 1 ? xq[i].y
                  : sub == 2 ? xq[i].z : xq[i].w;
#pragma unroll
          for (int j = 0; j < 8; ++j) za[i][j] = fmaf(x, w[j], za[i][j]);
        }
      }
    }
  }
  // bias + relu (cols cL+j for j<4, cH+j-4 for j>=4)
#pragma unroll
  for (int i = 0; i < 4; ++i) {
#pragma unroll
    for (int j = 0; j < 4; ++j) {
      za[i][j] = fmaxf(za[i][j] + ba[cL + j], 0.f);
      za[i][4 + j] = fmaxf(za[i][4 + j] + ba[cH + j], 0.f);
    }
  }

  // write za into LDS (Xs region is dead now), same swizzle
  __syncthreads();
  float* zaS = Xs;
  {
    int sL = (cL + (ty << 2)) & 127;
    int sH = (cH + (ty << 2)) & 127;
#pragma unroll
    for (int i = 0; i < 4; ++i) {
      *(float4*)&zaS[(r0 + i) * 128 + sL] =
          make_float4(za[i][0], za[i][1], za[i][2], za[i][3]);
      *(float4*)&zaS[(r0 + i) * 128 + sH] =
          make_float4(za[i][4], za[i][5], za[i][6], za[i][7]);
    }
  }

  const int c0b = tx * 4;  // zb cols (M2=64)
  float zb[4][4];
#pragma unroll
  for (int i = 0; i < 4; ++i)
#pragma unroll
    for (int j = 0; j < 4; ++j) zb[i][j] = 0.f;

  // zb accumulation: K=128 in two 64-row chunks of Wb (16KB LDS-staged)
  for (int chunk = 0; chunk < 2; ++chunk) {
    __syncthreads();
    const float4* Wb4 = (const float4*)(Wb + chunk * 64 * 64);
    float4* Wd = (float4*)Wbuf;
    for (int i = t; i < 1024; i += 256) Wd[i] = Wb4[i];
    __syncthreads();
    const int kb = chunk * 64;
    for (int k4 = 0; k4 < 16; ++k4) {
      const int kc = (kb + k4 * 4 + (ty << 2)) & 127;
      float4 xq[4];
#pragma unroll
      for (int i = 0; i < 4; ++i)
        xq[i] = *(const float4*)&zaS[(r0 + i) * 128 + kc];
#pragma unroll
      for (int sub = 0; sub < 4; ++sub) {
        const int kk = k4 * 4 + sub;
        float4 w = *(const float4*)&Wbuf[kk * 64 + c0b];  // stride-4: free
        const float wj[4] = {w.x, w.y, w.z, w.w};
#pragma unroll
        for (int i = 0; i < 4; ++i) {
          float x = sub == 0 ? xq[i].x : sub == 1 ? xq[i].y
                  : sub == 2 ? xq[i].z : xq[i].w;
#pragma unroll
          for (int j = 0; j < 4; ++j) zb[i][j] = fmaf(x, wj[j], zb[i][j]);
        }
      }
    }
  }
  // bias + relu + partial Wo dot
  float part[4];
#pragma unroll
  for (int i = 0; i < 4; ++i) {
    part[i] = 0.f;
#pragma unroll
    for (int j = 0; j < 4; ++j) {
      float v = fmaxf(zb[i][j] + bb[c0b + j], 0.f);
      part[i] = fmaf(v, Wo[c0b + j], part[i]);
    }
  }
  // reduce 16 partials per row via LDS (Wbuf is dead now)
  __syncthreads();
  float* red = Wbuf;
#pragma unroll
  for (int i = 0; i < 4; ++i) red[tx * 68 + r0 + i] = part[i];
  __syncthreads();
  if (t < 64) {
    int gr = row0 + t;
    if (gr < N) {
      float s = 0.f;
#pragma unroll
      for (int u = 0; u < 16; ++u) s += red[u * 68 + t];
      float w = s + bo[0];
      float p = 1.0f / (1.0f + expf(-w));
      unsigned i = (unsigned)gr;
      unsigned bits0 = jax_random_bits_u32(0u, 42u, 2u * i);
      unsigned bits1 = jax_random_bits_u32(0u, 42u, 2u * i + 1u);
      float f0 = __uint_as_float((bits0 >> 9) | 0x3f800000u) - 1.0f;
      float f1 = __uint_as_float((bits1 >> 9) | 0x3f800000u) - 1.0f;
      float u0 = fmaxf(1e-20f, f0 + 1e-20f);
      float u1 = fmaxf(1e-20f, f1 + 1e-20f);
      float g0 = -logf(-logf(u0));
      float g1 = -logf(-logf(u1));
      float a0 = (1.0f - p) + g0;
      float a1 = p + g1;
      float m = fmaxf(a0, a1);
      float e0 = expf(a0 - m), e1 = expf(a1 - m);
      float ssum = e0 + e1;
      float y0 = e0 / ssum, y1 = e1 / ssum;
      float hard1 = (y1 > y0) ? 1.0f : 0.0f;
      float st1 = (hard1 + y1) - y1;
      out[gr] = p;
      out[N + gr] = st1;
    }
  }
}

// ------------------------------- launcher ----------------------------------
extern "C" void kernel_launch(void* const* d_in, const int* in_sizes, int n_in,
                              void* d_out, int out_size, void* d_ws, size_t ws_size,
                              hipStream_t stream) {
  const float* rep = (const float*)d_in[0];
  const int* ei = (const int*)d_in[1];
  const float* W1 = (const float*)d_in[2];
  const float* b1 = (const float*)d_in[3];
  const float* W2 = (const float*)d_in[4];
  const float* b2 = (const float*)d_in[5];
  const float* Wa = (const float*)d_in[6];
  const float* ba = (const float*)d_in[7];
  const float* Wb = (const float*)d_in[8];
  const float* bb = (const float*)d_in[9];
  const float* Wo = (const float*)d_in[10];
  const float* bo = (const float*)d_in[11];
  float* out = (float*)d_out;

  const int N = in_sizes[0] / 64;   // < 2^20 (packing requirement)
  const int E = in_sizes[1] / 2;
  const int* srcI = ei;      // edge_index[0]
  const int* dstI = ei + E;  // edge_index[1]

  const int NBUCK = (N + 255) >> BSHIFT;  // <= 512

  // workspace layout
  float* ws = (float*)d_ws;
  float* bufA = ws;                          // N*64 (xws / scratch)
  float* bufB = bufA + (size_t)N * 64;       // N*64 (h1 / h2)
  float* dinv = bufB + (size_t)N * 64;       // N
  int* coarse = (int*)(dinv + N);            // 512
  int* bbase = coarse + 512;                 // 513
  int* cbase = bbase + 513;                  // 512
  int* off = cbase + 512;                    // N+1
  int* pkB = off + N + 1;                    // E (packed bucketed edges)
  int* srcS = pkB + E;                       // E (CSR src list)

  const int nb64 = (N + 63) / 64;
  const int nbW = (N + 3) / 4;
  const int nbA = (E + CHUNK - 1) / CHUNK;

  // ---- bucketed CSR build + dinv
  hipMemsetAsync(coarse, 0, 512 * 4, stream);
  coarse_hist_kernel<<<256, 256, 0, stream>>>(dstI, coarse, E);
  coarse_scan_kernel<<<1, 512, 0, stream>>>(coarse, bbase, cbase, NBUCK);
  bucket_scatter_kernel<<<nbA, 256, 0, stream>>>(srcI, dstI, cbase, pkB, E);
  bucket_finalize_kernel<<<NBUCK, 256, 0, stream>>>(pkB, bbase, off, dinv,
                                                    srcS, N);

  // ---- GCN layer 1: bufA = dinv*(rep@W1); bufB = relu(agg + self + b1)
  gemm64v2_kernel<<<nb64, 256, 0, stream>>>(rep, W1, dinv, bufA, N, 8);
  aggregate_kernel<<<nbW, 256, 0, stream>>>(bufA, srcS, off, dinv, b1, bufB, N);

  // ---- GCN layer 2
  gemm64v2_kernel<<<nb64, 256, 0, stream>>>(bufB, W2, dinv, bufA, N, 8);
  aggregate_kernel<<<nbW, 256, 0, stream>>>(bufA, srcS, off, dinv, b2, bufB, N);

  // ---- fused head: za -> zb -> prob -> gumbel indicator
  head_mega_kernel<<<nb64, 256, 0, stream>>>(rep, bufB, Wa, ba, Wb, bb, Wo, bo,
                                             out, N);
}

// Round 12
// 387.145 us; speedup vs baseline: 1.3776x; 1.0270x over previous
//
#include <hip/hip_runtime.h>
#include <math.h>

// ---------------------------------------------------------------------------
// GraphNewPolicyNetwork: 2x GCNConv(improved=True) + MLP head + sigmoid +
// gumbel-softmax(hard) straight-through indicator.
// N=100000 nodes, E=1600000 edges, D=H1=H2=64, M1=128, M2=64.
// Outputs: d_out[0:N] = prob (f32), d_out[N:2N] = ind (f32, 0/1).
//
// Round 12: head reverted to round-9 form (VGPR 68; quad-k variant raised
// VGPR to 88 and lost occupancy). gemm1 made dependency-free by moving the
// dinv prescale into layer-1 aggregate (per-edge dinv[s] gather, bitwise-
// equivalent product), then grid-fused into the bucket_scatter dispatch.
// ---------------------------------------------------------------------------

// ----------------------------- threefry2x32 --------------------------------
__device__ __forceinline__ unsigned rotl32(unsigned x, int r) {
  return (x << r) | (x >> (32 - r));
}

// JAX threefry2x32 (20 rounds), matches jax/_src/prng.py
__device__ __forceinline__ void threefry2x32(unsigned k0, unsigned k1,
                                             unsigned x0, unsigned x1,
                                             unsigned& o0, unsigned& o1) {
  unsigned ks2 = k0 ^ k1 ^ 0x1BD11BDAu;
#define TF_RND(r) { x0 += x1; x1 = rotl32(x1, (r)); x1 ^= x0; }
  x0 += k0; x1 += k1;
  TF_RND(13) TF_RND(15) TF_RND(26) TF_RND(6)
  x0 += k1; x1 += ks2 + 1u;
  TF_RND(17) TF_RND(29) TF_RND(16) TF_RND(24)
  x0 += ks2; x1 += k0 + 2u;
  TF_RND(13) TF_RND(15) TF_RND(26) TF_RND(6)
  x0 += k0; x1 += k1 + 3u;
  TF_RND(17) TF_RND(29) TF_RND(16) TF_RND(24)
  x0 += k1; x1 += ks2 + 4u;
  TF_RND(13) TF_RND(15) TF_RND(26) TF_RND(6)
  x0 += ks2; x1 += k0 + 5u;
#undef TF_RND
  o0 = x0; o1 = x1;
}

// Partitionable threefry bits: element flat index j -> counter (0, j),
// 32-bit output = out0 ^ out1.
__device__ __forceinline__ unsigned jax_random_bits_u32(unsigned k0, unsigned k1,
                                                        unsigned flat_idx) {
  unsigned a, b;
  threefry2x32(k0, k1, 0u, flat_idx, a, b);
  return a ^ b;
}

// --------------------------- bucketed CSR build ----------------------------
// bucket(d) = d >> 8  (256 nodes per bucket, NBUCK = ceil(N/256) <= 512).
// Packed edge: (dlocal << 20) | src   (requires src < 2^20, dlocal < 2^12).
#define BSHIFT 8
#define BMASK 255

// Per-block LDS histogram of buckets, merged into global coarse[].
__global__ __launch_bounds__(256) void coarse_hist_kernel(
    const int* __restrict__ dst, int* __restrict__ coarse, int E) {
  __shared__ int h[512];
  for (int i = threadIdx.x; i < 512; i += 256) h[i] = 0;
  __syncthreads();
  for (int e = blockIdx.x * blockDim.x + threadIdx.x; e < E;
       e += gridDim.x * blockDim.x)
    atomicAdd(&h[dst[e] >> BSHIFT], 1);
  __syncthreads();
  for (int i = threadIdx.x; i < 512; i += 256)
    if (h[i]) atomicAdd(&coarse[i], h[i]);
}

// Single block: exclusive scan of coarse -> bbase (bucket ranges) and cbase
// (scatter cursors).
__global__ __launch_bounds__(512) void coarse_scan_kernel(
    const int* __restrict__ coarse, int* __restrict__ bbase,
    int* __restrict__ cbase, int NBUCK) {
  __shared__ int sh[512];
  int t = threadIdx.x;
  int v = (t < NBUCK) ? coarse[t] : 0;
  sh[t] = v;
  __syncthreads();
  for (int o = 1; o < 512; o <<= 1) {
    int a = (t >= o) ? sh[t - o] : 0;
    __syncthreads();
    sh[t] += a;
    __syncthreads();
  }
  if (t < NBUCK) {
    int ex = sh[t] - v;
    bbase[t] = ex;
    cbase[t] = ex;
    if (t == NBUCK - 1) bbase[NBUCK] = sh[t];
  }
}

// ------------- fused dispatch: bucket scatter  ||  gemm1 (raw) --------------
// Blocks [0, nbA): scatter packed edges into bucket-contiguous pkB.
// Blocks [nbA, nbA+nb64): Y = rep @ W1 (RAW — no dinv; applied in agg).
// Independent work grid-fused so gemm1's VALU hides behind scatter's memory.
#define CHUNK 4096
__global__ __launch_bounds__(256) void scatter_gemm_kernel(
    const int* __restrict__ src, const int* __restrict__ dst,
    int* __restrict__ cbase, int* __restrict__ pkB, int E, int nbA,
    const float* __restrict__ X, const float* __restrict__ W,
    float* __restrict__ Y, int N) {
  __shared__ int smem[9216];  // 36 KB union (scatter 36 KB / gemm 33.8 KB)
  const int t = threadIdx.x;

  if (blockIdx.x < nbA) {
    // ---------------- scatter branch ----------------
    int* sS = smem;            // 4096
    int* dS = smem + 4096;     // 4096
    int* cnt = smem + 8192;    // 512
    int* base = smem + 8704;   // 512
    const int e0 = blockIdx.x * CHUNK;
    const int n = min(CHUNK, E - e0);
    for (int i = t; i < 512; i += 256) cnt[i] = 0;
    for (int i = t; i < n; i += 256) {
      sS[i] = src[e0 + i];
      dS[i] = dst[e0 + i];
    }
    __syncthreads();
    for (int i = t; i < n; i += 256) atomicAdd(&cnt[dS[i] >> BSHIFT], 1);
    __syncthreads();
    for (int i = t; i < 512; i += 256) {
      int c = cnt[i];
      base[i] = c ? atomicAdd(&cbase[i], c) : 0;
    }
    __syncthreads();
    for (int i = t; i < 512; i += 256) cnt[i] = 0;
    __syncthreads();
    for (int i = t; i < n; i += 256) {
      int d = dS[i];
      int b = d >> BSHIFT;
      int r = atomicAdd(&cnt[b], 1);
      pkB[base[b] + r] = ((d & BMASK) << 20) | sS[i];
    }
    return;
  }

  // ---------------- gemm branch (raw X@W) ----------------
  float* Ws = (float*)smem;          // 64*64
  float* Xs = (float*)smem + 4096;   // 64*68
  {
    const float4* W4 = (const float4*)W;
    float4* Ws4 = (float4*)Ws;
    for (int i = t; i < 1024; i += 256) Ws4[i] = W4[i];
  }
  const int row0 = (blockIdx.x - nbA) * 64;
  for (int i = t; i < 64 * 16; i += 256) {
    int r = i >> 4, c4 = i & 15;
    int gr = row0 + r;
    float4 v = make_float4(0.f, 0.f, 0.f, 0.f);
    if (gr < N) v = *(const float4*)&X[(size_t)gr * 64 + c4 * 4];
    *(float4*)&Xs[r * 68 + c4 * 4] = v;
  }
  __syncthreads();

  const int tx = t & 15, ty = t >> 4;
  const int c0 = tx * 4;
  const int r0 = ty * 4;
  float acc[4][4];
#pragma unroll
  for (int i = 0; i < 4; ++i)
#pragma unroll
    for (int j = 0; j < 4; ++j) acc[i][j] = 0.f;

#pragma unroll 4
  for (int k4 = 0; k4 < 16; ++k4) {
    float4 xv[4];
#pragma unroll
    for (int i = 0; i < 4; ++i)
      xv[i] = *(const float4*)&Xs[(r0 + i) * 68 + k4 * 4];
#pragma unroll
    for (int kk = 0; kk < 4; ++kk) {
      float w[4];
#pragma unroll
      for (int j = 0; j < 4; ++j) w[j] = Ws[(k4 * 4 + kk) * 64 + c0 + j];
      const float xk[4] = {
          kk == 0 ? xv[0].x : kk == 1 ? xv[0].y : kk == 2 ? xv[0].z : xv[0].w,
          kk == 0 ? xv[1].x : kk == 1 ? xv[1].y : kk == 2 ? xv[1].z : xv[1].w,
          kk == 0 ? xv[2].x : kk == 1 ? xv[2].y : kk == 2 ? xv[2].z : xv[2].w,
          kk == 0 ? xv[3].x : kk == 1 ? xv[3].y : kk == 2 ? xv[3].z : xv[3].w};
#pragma unroll
      for (int i = 0; i < 4; ++i)
#pragma unroll
        for (int j = 0; j < 4; ++j) acc[i][j] = fmaf(xk[i], w[j], acc[i][j]);
    }
  }

#pragma unroll
  for (int i = 0; i < 4; ++i) {
    int gr = row0 + r0 + i;
    if (gr >= N) continue;
    float4 v = make_float4(acc[i][0], acc[i][1], acc[i][2], acc[i][3]);
    *(float4*)&Y[(size_t)gr * 64 + c0] = v;
  }
}

// Fused per-bucket finalize: LDS deg-hist -> LDS scan -> off/dinv/cursor ->
// CSR scatter. One block per bucket.
__global__ __launch_bounds__(256) void bucket_finalize_kernel(
    const int* __restrict__ pkB, const int* __restrict__ bbase,
    int* __restrict__ off, float* __restrict__ dinv, int* __restrict__ srcS,
    int N) {
  __shared__ int cnt[256];
  __shared__ int sh[256];
  const int t = threadIdx.x;
  const int b = blockIdx.x;
  const int lo = bbase[b], hi = bbase[b + 1];
  cnt[t] = 0;
  __syncthreads();
  for (int i = lo + t; i < hi; i += 256) atomicAdd(&cnt[pkB[i] >> 20], 1);
  __syncthreads();
  const int deg = cnt[t];
  sh[t] = deg;
  __syncthreads();
  for (int o = 1; o < 256; o <<= 1) {
    int a = (t >= o) ? sh[t - o] : 0;
    __syncthreads();
    sh[t] += a;
    __syncthreads();
  }
  const int ex = sh[t] - deg;  // exclusive prefix within bucket
  const int node = (b << BSHIFT) + t;
  if (node < N) {
    off[node] = lo + ex;
    dinv[node] = 1.0f / sqrtf((float)deg + 2.0f);
    if (node == N - 1) off[N] = hi;
  }
  cnt[t] = lo + ex;  // cursor
  __syncthreads();
  for (int i = lo + t; i < hi; i += 256) {
    int u = pkB[i];
    int pos = atomicAdd(&cnt[u >> 20], 1);
    srcS[pos] = u & 0xFFFFF;
  }
}

// ---------------------------- aggregation ----------------------------------
// One wave per dst node. g = lane>>4 (edge group), fq = lane&15 (float4
// chunk). Masked 16-edge loop keeps 4 gathers in flight.
// If dinvS != null (layer 1, raw xw): each edge row is scaled by dinv[src]
// in-register (same single-rounded product the prescale produced) and the
// self row by dinv[node].
__global__ __launch_bounds__(256) void aggregate_kernel(
    const float* __restrict__ xws, const int* __restrict__ srcS,
    const int* __restrict__ off, const float* __restrict__ dinv,
    const float* __restrict__ dinvS, const float* __restrict__ bias,
    float* __restrict__ h, int N) {
  int node = (blockIdx.x * blockDim.x + threadIdx.x) >> 6;
  int lane = threadIdx.x & 63;
  int g = lane >> 4;   // edge group
  int fq = lane & 15;  // float4 index within row
  if (node >= N) return;
  const float4* xw4 = (const float4*)xws;  // row stride = 16 float4
  int beg = off[node], end = off[node + 1];
  float4 a0 = make_float4(0.f, 0.f, 0.f, 0.f);
  float4 a1 = a0, a2 = a0, a3 = a0;
  if (dinvS) {
    for (int e = beg; e < end; e += 16) {
      int e0 = e + g, e1 = e + 4 + g, e2 = e + 8 + g, e3 = e + 12 + g;
      int s0 = srcS[min(e0, end - 1)];
      int s1 = srcS[min(e1, end - 1)];
      int s2 = srcS[min(e2, end - 1)];
      int s3 = srcS[min(e3, end - 1)];
      float d0 = dinvS[s0], d1 = dinvS[s1], d2 = dinvS[s2], d3 = dinvS[s3];
      float4 v0 = xw4[(size_t)s0 * 16 + fq];
      float4 v1 = xw4[(size_t)s1 * 16 + fq];
      float4 v2 = xw4[(size_t)s2 * 16 + fq];
      float4 v3 = xw4[(size_t)s3 * 16 + fq];
      if (e0 < end) { a0.x += d0*v0.x; a0.y += d0*v0.y; a0.z += d0*v0.z; a0.w += d0*v0.w; }
      if (e1 < end) { a1.x += d1*v1.x; a1.y += d1*v1.y; a1.z += d1*v1.z; a1.w += d1*v1.w; }
      if (e2 < end) { a2.x += d2*v2.x; a2.y += d2*v2.y; a2.z += d2*v2.z; a2.w += d2*v2.w; }
      if (e3 < end) { a3.x += d3*v3.x; a3.y += d3*v3.y; a3.z += d3*v3.z; a3.w += d3*v3.w; }
    }
  } else {
    for (int e = beg; e < end; e += 16) {
      int e0 = e + g, e1 = e + 4 + g, e2 = e + 8 + g, e3 = e + 12 + g;
      int s0 = srcS[min(e0, end - 1)];
      int s1 = srcS[min(e1, end - 1)];
      int s2 = srcS[min(e2, end - 1)];
      int s3 = srcS[min(e3, end - 1)];
      float4 v0 = xw4[(size_t)s0 * 16 + fq];
      float4 v1 = xw4[(size_t)s1 * 16 + fq];
      float4 v2 = xw4[(size_t)s2 * 16 + fq];
      float4 v3 = xw4[(size_t)s3 * 16 + fq];
      if (e0 < end) { a0.x += v0.x; a0.y += v0.y; a0.z += v0.z; a0.w += v0.w; }
      if (e1 < end) { a1.x += v1.x; a1.y += v1.y; a1.z += v1.z; a1.w += v1.w; }
      if (e2 < end) { a2.x += v2.x; a2.y += v2.y; a2.z += v2.z; a2.w += v2.w; }
      if (e3 < end) { a3.x += v3.x; a3.y += v3.y; a3.z += v3.z; a3.w += v3.w; }
    }
  }
  float4 a;
  a.x = (a0.x + a1.x) + (a2.x + a3.x);
  a.y = (a0.y + a1.y) + (a2.y + a3.y);
  a.z = (a0.z + a1.z) + (a2.z + a3.z);
  a.w = (a0.w + a1.w) + (a2.w + a3.w);
  // merge the 4 edge groups (lanes fq, 16+fq, 32+fq, 48+fq)
  a.x += __shfl_xor(a.x, 16, 64); a.x += __shfl_xor(a.x, 32, 64);
  a.y += __shfl_xor(a.y, 16, 64); a.y += __shfl_xor(a.y, 32, 64);
  a.z += __shfl_xor(a.z, 16, 64); a.z += __shfl_xor(a.z, 32, 64);
  a.w += __shfl_xor(a.w, 16, 64); a.w += __shfl_xor(a.w, 32, 64);
  if (g == 0) {
    float di = dinv[node];
    float4 self = xw4[(size_t)node * 16 + fq];
    if (dinvS) { self.x *= di; self.y *= di; self.z *= di; self.w *= di; }
    float4 b = ((const float4*)bias)[fq];
    float4 r;
    r.x = fmaxf(di * (a.x + 2.0f * self.x) + b.x, 0.f);
    r.y = fmaxf(di * (a.y + 2.0f * self.y) + b.y, 0.f);
    r.z = fmaxf(di * (a.z + 2.0f * self.z) + b.z, 0.f);
    r.w = fmaxf(di * (a.w + 2.0f * self.w) + b.w, 0.f);
    *(float4*)&h[(size_t)node * 64 + fq * 4] = r;
  }
}

// ------------------------------- GEMM (K2) ----------------------------------
// Y = dinv[row] * (X @ W), register-tiled, float4 epilogue. Xs pad 68.
__global__ __launch_bounds__(256) void gemm64v2_kernel(
    const float* __restrict__ X, const float* __restrict__ W,
    const float* __restrict__ dinv, float* __restrict__ Y, int N) {
  __shared__ float Ws[64 * 64];
  __shared__ float Xs[64 * 68];
  const int t = threadIdx.x;
  {
    const float4* W4 = (const float4*)W;
    float4* Ws4 = (float4*)Ws;
    for (int i = t; i < 16 * 64; i += 256) Ws4[i] = W4[i];
  }
  const int row0 = blockIdx.x * 64;
  for (int i = t; i < 64 * 16; i += 256) {
    int r = i >> 4, c4 = i & 15;
    int gr = row0 + r;
    float4 v = make_float4(0.f, 0.f, 0.f, 0.f);
    if (gr < N) v = *(const float4*)&X[(size_t)gr * 64 + c4 * 4];
    *(float4*)&Xs[r * 68 + c4 * 4] = v;
  }
  __syncthreads();

  const int tx = t & 15, ty = t >> 4;
  const int c0 = tx * 4;
  const int r0 = ty * 4;
  float acc[4][4];
#pragma unroll
  for (int i = 0; i < 4; ++i)
#pragma unroll
    for (int j = 0; j < 4; ++j) acc[i][j] = 0.f;

#pragma unroll 4
  for (int k4 = 0; k4 < 16; ++k4) {
    float4 xv[4];
#pragma unroll
    for (int i = 0; i < 4; ++i)
      xv[i] = *(const float4*)&Xs[(r0 + i) * 68 + k4 * 4];
#pragma unroll
    for (int kk = 0; kk < 4; ++kk) {
      float w[4];
#pragma unroll
      for (int j = 0; j < 4; ++j) w[j] = Ws[(k4 * 4 + kk) * 64 + c0 + j];
      const float xk[4] = {
          kk == 0 ? xv[0].x : kk == 1 ? xv[0].y : kk == 2 ? xv[0].z : xv[0].w,
          kk == 0 ? xv[1].x : kk == 1 ? xv[1].y : kk == 2 ? xv[1].z : xv[1].w,
          kk == 0 ? xv[2].x : kk == 1 ? xv[2].y : kk == 2 ? xv[2].z : xv[2].w,
          kk == 0 ? xv[3].x : kk == 1 ? xv[3].y : kk == 2 ? xv[3].z : xv[3].w};
#pragma unroll
      for (int i = 0; i < 4; ++i)
#pragma unroll
        for (int j = 0; j < 4; ++j) acc[i][j] = fmaf(xk[i], w[j], acc[i][j]);
    }
  }

#pragma unroll
  for (int i = 0; i < 4; ++i) {
    int gr = row0 + r0 + i;
    if (gr >= N) continue;
    float sc = dinv[gr];
    float4 v = make_float4(acc[i][0] * sc, acc[i][1] * sc, acc[i][2] * sc,
                           acc[i][3] * sc);
    *(float4*)&Y[(size_t)gr * 64 + c0] = v;
  }
}

// --------------------------- fused head kernel -----------------------------
// Round-9 configuration (measured: ~106 us, SQ_LDS_BANK_CONFLICT = 0,
// VGPR 68, occupancy 24.6%): 256 threads, 4 rows x 8 cols/thread.
// Xs/zaS swizzle: (r,c) at r*128 + ((c + (r>>2)*4) & 127). W cols split
// {tx*4, 64+tx*4} -> stride-4 b128 (free 2-way). Wbuf 16KB chunked staging.
// LDS 48KB -> 3 blocks/CU.
__global__ __launch_bounds__(256) void head_mega_kernel(
    const float* __restrict__ rep, const float* __restrict__ h2,
    const float* __restrict__ Wa, const float* __restrict__ ba,
    const float* __restrict__ Wb, const float* __restrict__ bb,
    const float* __restrict__ Wo, const float* __restrict__ bo,
    float* __restrict__ out, int N) {
  __shared__ float Xs[64 * 128];    // 32 KB swizzled ([rep,h2]; later zaS)
  __shared__ float Wbuf[32 * 128];  // 16 KB weight staging; later reduction
  const int t = threadIdx.x;
  const int row0 = blockIdx.x * 64;

  // stage [rep, h2] tile (64 x 128), swizzled, coalesced float4
  for (int i = t; i < 2048; i += 256) {
    int r = i >> 5, c4 = i & 31;
    int gr = row0 + r;
    float4 v = make_float4(0.f, 0.f, 0.f, 0.f);
    if (gr < N)
      v = (c4 < 16) ? *(const float4*)&rep[(size_t)gr * 64 + c4 * 4]
                    : *(const float4*)&h2[(size_t)gr * 64 + (c4 - 16) * 4];
    int scol = (c4 * 4 + ((r >> 2) << 2)) & 127;
    *(float4*)&Xs[r * 128 + scol] = v;
  }

  const int tx = t & 15, ty = t >> 4;
  const int cL = tx * 4;        // low-half za cols
  const int cH = 64 + tx * 4;   // high-half za cols
  const int r0 = ty * 4;        // rows; (r0+i)>>2 == ty
  float za[4][8];
#pragma unroll
  for (int i = 0; i < 4; ++i)
#pragma unroll
    for (int j = 0; j < 8; ++j) za[i][j] = 0.f;

  // za accumulation: K=128 in four 32-row chunks of Wa (16KB LDS-staged)
  for (int chunk = 0; chunk < 4; ++chunk) {
    __syncthreads();
    const float4* Wa4 = (const float4*)(Wa + chunk * 32 * 128);
    float4* Wd = (float4*)Wbuf;
    for (int i = t; i < 1024; i += 256) Wd[i] = Wa4[i];
    __syncthreads();
    const int kb = chunk * 32;
#pragma unroll 2
    for (int kk = 0; kk < 32; ++kk) {
      const int kc = (kb + kk + (ty << 2)) & 127;  // swizzled col
      float x[4];
#pragma unroll
      for (int i = 0; i < 4; ++i) x[i] = Xs[(r0 + i) * 128 + kc];
      float4 w0 = *(const float4*)&Wbuf[kk * 128 + cL];  // stride-4: free
      float4 w1 = *(const float4*)&Wbuf[kk * 128 + cH];  // stride-4: free
      const float w[8] = {w0.x, w0.y, w0.z, w0.w, w1.x, w1.y, w1.z, w1.w};
#pragma unroll
      for (int i = 0; i < 4; ++i)
#pragma unroll
        for (int j = 0; j < 8; ++j) za[i][j] = fmaf(x[i], w[j], za[i][j]);
    }
  }
  // bias + relu (cols cL+j for j<4, cH+j-4 for j>=4)
#pragma unroll
  for (int i = 0; i < 4; ++i) {
#pragma unroll
    for (int j = 0; j < 4; ++j) {
      za[i][j] = fmaxf(za[i][j] + ba[cL + j], 0.f);
      za[i][4 + j] = fmaxf(za[i][4 + j] + ba[cH + j], 0.f);
    }
  }

  // write za into LDS (Xs region is dead now), same swizzle
  __syncthreads();
  float* zaS = Xs;
  {
    int sL = (cL + (ty << 2)) & 127;
    int sH = (cH + (ty << 2)) & 127;
#pragma unroll
    for (int i = 0; i < 4; ++i) {
      *(float4*)&zaS[(r0 + i) * 128 + sL] =
          make_float4(za[i][0], za[i][1], za[i][2], za[i][3]);
      *(float4*)&zaS[(r0 + i) * 128 + sH] =
          make_float4(za[i][4], za[i][5], za[i][6], za[i][7]);
    }
  }

  const int c0b = tx * 4;  // zb cols (M2=64)
  float zb[4][4];
#pragma unroll
  for (int i = 0; i < 4; ++i)
#pragma unroll
    for (int j = 0; j < 4; ++j) zb[i][j] = 0.f;

  // zb accumulation: K=128 in two 64-row chunks of Wb (16KB LDS-staged)
  for (int chunk = 0; chunk < 2; ++chunk) {
    __syncthreads();
    const float4* Wb4 = (const float4*)(Wb + chunk * 64 * 64);
    float4* Wd = (float4*)Wbuf;
    for (int i = t; i < 1024; i += 256) Wd[i] = Wb4[i];
    __syncthreads();
    const int kb = chunk * 64;
#pragma unroll 4
    for (int kk = 0; kk < 64; ++kk) {
      const int kc = (kb + kk + (ty << 2)) & 127;
      float x[4];
#pragma unroll
      for (int i = 0; i < 4; ++i) x[i] = zaS[(r0 + i) * 128 + kc];
      float4 w = *(const float4*)&Wbuf[kk * 64 + c0b];  // stride-4: free
      const float wj[4] = {w.x, w.y, w.z, w.w};
#pragma unroll
      for (int i = 0; i < 4; ++i)
#pragma unroll
        for (int j = 0; j < 4; ++j) zb[i][j] = fmaf(x[i], wj[j], zb[i][j]);
    }
  }
  // bias + relu + partial Wo dot
  float part[4];
#pragma unroll
  for (int i = 0; i < 4; ++i) {
    part[i] = 0.f;
#pragma unroll
    for (int j = 0; j < 4; ++j) {
      float v = fmaxf(zb[i][j] + bb[c0b + j], 0.f);
      part[i] = fmaf(v, Wo[c0b + j], part[i]);
    }
  }
  // reduce 16 partials per row via LDS (Wbuf is dead now)
  __syncthreads();
  float* red = Wbuf;
#pragma unroll
  for (int i = 0; i < 4; ++i) red[tx * 68 + r0 + i] = part[i];
  __syncthreads();
  if (t < 64) {
    int gr = row0 + t;
    if (gr < N) {
      float s = 0.f;
#pragma unroll
      for (int u = 0; u < 16; ++u) s += red[u * 68 + t];
      float w = s + bo[0];
      float p = 1.0f / (1.0f + expf(-w));
      unsigned i = (unsigned)gr;
      unsigned bits0 = jax_random_bits_u32(0u, 42u, 2u * i);
      unsigned bits1 = jax_random_bits_u32(0u, 42u, 2u * i + 1u);
      float f0 = __uint_as_float((bits0 >> 9) | 0x3f800000u) - 1.0f;
      float f1 = __uint_as_float((bits1 >> 9) | 0x3f800000u) - 1.0f;
      float u0 = fmaxf(1e-20f, f0 + 1e-20f);
      float u1 = fmaxf(1e-20f, f1 + 1e-20f);
      float g0 = -logf(-logf(u0));
      float g1 = -logf(-logf(u1));
      float a0 = (1.0f - p) + g0;
      float a1 = p + g1;
      float m = fmaxf(a0, a1);
      float e0 = expf(a0 - m), e1 = expf(a1 - m);
      float ssum = e0 + e1;
      float y0 = e0 / ssum, y1 = e1 / ssum;
      float hard1 = (y1 > y0) ? 1.0f : 0.0f;
      float st1 = (hard1 + y1) - y1;
      out[gr] = p;
      out[N + gr] = st1;
    }
  }
}

// ------------------------------- launcher ----------------------------------
extern "C" void kernel_launch(void* const* d_in, const int* in_sizes, int n_in,
                              void* d_out, int out_size, void* d_ws, size_t ws_size,
                              hipStream_t stream) {
  const float* rep = (const float*)d_in[0];
  const int* ei = (const int*)d_in[1];
  const float* W1 = (const float*)d_in[2];
  const float* b1 = (const float*)d_in[3];
  const float* W2 = (const float*)d_in[4];
  const float* b2 = (const float*)d_in[5];
  const float* Wa = (const float*)d_in[6];
  const float* ba = (const float*)d_in[7];
  const float* Wb = (const float*)d_in[8];
  const float* bb = (const float*)d_in[9];
  const float* Wo = (const float*)d_in[10];
  const float* bo = (const float*)d_in[11];
  float* out = (float*)d_out;

  const int N = in_sizes[0] / 64;   // < 2^20 (packing requirement)
  const int E = in_sizes[1] / 2;
  const int* srcI = ei;      // edge_index[0]
  const int* dstI = ei + E;  // edge_index[1]

  const int NBUCK = (N + 255) >> BSHIFT;  // <= 512

  // workspace layout
  float* ws = (float*)d_ws;
  float* bufA = ws;                          // N*64 (xw1 raw / xws2)
  float* bufB = bufA + (size_t)N * 64;       // N*64 (h1 / h2)
  float* dinv = bufB + (size_t)N * 64;       // N
  int* coarse = (int*)(dinv + N);            // 512
  int* bbase = coarse + 512;                 // 513
  int* cbase = bbase + 513;                  // 512
  int* off = cbase + 512;                    // N+1
  int* pkB = off + N + 1;                    // E (packed bucketed edges)
  int* srcS = pkB + E;                       // E (CSR src list)

  const int nb64 = (N + 63) / 64;
  const int nbW = (N + 3) / 4;
  const int nbA = (E + CHUNK - 1) / CHUNK;

  // ---- CSR build (hist -> scan -> [scatter || gemm1 raw] -> finalize)
  hipMemsetAsync(coarse, 0, 512 * 4, stream);
  coarse_hist_kernel<<<256, 256, 0, stream>>>(dstI, coarse, E);
  coarse_scan_kernel<<<1, 512, 0, stream>>>(coarse, bbase, cbase, NBUCK);
  scatter_gemm_kernel<<<nbA + nb64, 256, 0, stream>>>(
      srcI, dstI, cbase, pkB, E, nbA, rep, W1, bufA, N);
  bucket_finalize_kernel<<<NBUCK, 256, 0, stream>>>(pkB, bbase, off, dinv,
                                                    srcS, N);

  // ---- GCN layer 1: bufB = relu(dinv.*(agg(dinv[s].*xw1) + 2*dinv*xw1) + b1)
  aggregate_kernel<<<nbW, 256, 0, stream>>>(bufA, srcS, off, dinv, dinv, b1,
                                            bufB, N);

  // ---- GCN layer 2: bufA = dinv * (h1 @ W2); bufB = relu(agg + self + b2)
  gemm64v2_kernel<<<nb64, 256, 0, stream>>>(bufB, W2, dinv, bufA, N);
  aggregate_kernel<<<nbW, 256, 0, stream>>>(bufA, srcS, off, dinv, nullptr, b2,
                                            bufB, N);

  // ---- fused head: za -> zb -> prob -> gumbel indicator
  head_mega_kernel<<<nb64, 256, 0, stream>>>(rep, bufB, Wa, ba, Wb, bb, Wo, bo,
                                             out, N);
}